// Round 4
// baseline (394.128 us; speedup 1.0000x reference)
//
#include <hip/hip_runtime.h>

// TALayer: deformable 1D conv, fixed integer taps d[j] ∈ {-17,-16,-15,-1,0,1,15,16,17}
// out[b,o,t] = sum_{c,j} W[o,c,j] * x[b,c,t+d[j]] (zero-pad OOB) + bias[o]
// B=8, C=O=64, T=65536. bf16 MFMA GEMM: C[64, B*T] = W[64,576] * Xg[576, B*T].
// R5: WRITE_SIZE 3x w/ nt-stores, 34% HBM, MfmaUtil 7%.
// R6: plain stores (no WRITE change); batched stage loads 215->197us.
// R7: launch_bounds(256,3) + K-loop 1-chunk pipeline + XCD swizzle: 197->133us.
//     WRITE fixed to 1.19x (3x was XCD write-locality, not store policy); FETCH 82MB
//     (x L3-resident). Now latency-bound: 23% HBM, MfmaUtil 11%, occ 26%.
// R8: tile-level software pipeline. Persistent blocks own 4 consecutive t-tiles;
//     next tile's global loads ISSUE before the K-loop (regs), COMMIT (cvt+ds_write)
//     during epilogue p=0 while xs is dead. os gets its own LDS region (73.5KB tot,
//     2 blocks/CU). Stage HBM latency hides under MFMA+epilogue; stores overlap
//     next tile's loads. launch_bounds(256,2): ~224/256 regs, 8 waves/CU (~= the
//     2 blocks/CU we already measured, so no TLP loss).

typedef short bf16x8 __attribute__((ext_vector_type(8)));   // 8 bf16 (4 VGPRs)
typedef short bf16x4 __attribute__((ext_vector_type(4)));   // 4 bf16 (8 B, ds_read_b64)
typedef float f32x4  __attribute__((ext_vector_type(4)));   // MFMA accumulator / 16B vec

#define T_LEN   65536
#define NT      256           // t-tile
#define NTILE   4             // tiles per block (pipelined)
#define SPAN    (NT * NTILE)  // 1024 t per block
#define ROWS    296           // staged rows: global t in [t0-20, t0+276)
#define PITCH   68            // shorts per LDS row (136 B)
#define LOFF    20            // x[t] -> LDS row (t - t0 + 20)
#define NCHUNK  18            // K = 576 = 18 * 32
#define OPITCH  260           // floats per epilogue LDS row
#define XS_SHORTS (ROWS * PITCH)   // 20128 shorts = 40,256 B
#define OS_FLOATS (32 * OPITCH)    // 8320 floats  = 33,280 B

__device__ __forceinline__ short f2bf(float f) {
    union { float f; unsigned u; } v; v.f = f;
    unsigned u = v.u;
    u += 0x7fffu + ((u >> 16) & 1u);   // round-to-nearest-even
    return (short)(u >> 16);
}

// Weight -> MFMA A-fragment order (bf16), layout [ch][mt][lane][8]:
// W2[((ch*4 + mt)*64 + lane)*8 + i] = bf16(W[o = mt*16 + (lane&15)][kk = ch*32 + (lane>>4)*8 + i])
__global__ void prep_w_kernel(const float* __restrict__ w, short* __restrict__ W2) {
    int idx = blockIdx.x * 256 + threadIdx.x;       // 0 .. 4607
    if (idx >= 4 * NCHUNK * 64) return;
    int lane = idx & 63;
    int g    = idx >> 6;            // ch*4 + mt
    int ch   = g >> 2;
    int mt   = g & 3;
    int o    = mt * 16 + (lane & 15);
    bf16x8 v;
#pragma unroll
    for (int i = 0; i < 8; ++i) {
        int kk = ch * 32 + (lane >> 4) * 8 + i;
        int j = kk >> 6, c = kk & 63;
        v[i] = f2bf(w[o * 576 + c * 9 + j]);
    }
    *(bf16x8*)(W2 + (size_t)idx * 8) = v;
}

__global__ __launch_bounds__(256, 2)
void ta_main_kernel(const float* __restrict__ x, const short* __restrict__ W2,
                    const float* __restrict__ bias, float* __restrict__ out) {
    __shared__ __align__(16) short xs[XS_SHORTS];   // staging: [tt][c] bf16, pitch 68
    __shared__ __align__(16) float os[OS_FLOATS];   // epilogue: [o_local][t] f32

    const int tid  = threadIdx.x;
    const int wv   = tid >> 6;                      // wave -> t-quadrant
    const int lane = tid & 63;
    const int l15  = lane & 15;
    const int quad = lane >> 4;
    const int b    = blockIdx.y;
    // XCD swizzle: linear dispatch id % 8 = bx % 8 (gridDim.x=64). Each XCD gets
    // a contiguous span of 8 groups (8*1024 t): halo L2 reuse + contiguous writes.
    const int bxd  = blockIdx.x;                    // 0..63
    const int bx   = (bxd & 7) * 8 + (bxd >> 3);
    const int tg0  = bx * SPAN;

    const int c = tid >> 2;
    const int q = tid & 3;
    const float* xrow = x + (((size_t)(b * 64 + c)) << 16);

    f32x4 v[19];                                    // staged tile in flight

    // issue: fire the ~19 independent f32x4 loads for tile at t0 (no waits here)
    auto issue = [&](const int t0) {
        const int tbase = t0 - LOFF;
        const bool interior = (t0 >= LOFF) && (t0 + (ROWS - LOFF) <= T_LEN);
        if (interior) {
#pragma unroll
            for (int i = 0; i < 19; ++i) {
                const int f = q + 4 * i;
                if (f < 74) v[i] = *(const f32x4*)(xrow + tbase + 4 * f);
            }
        } else {
#pragma unroll
            for (int i = 0; i < 19; ++i) {
                const int f = q + 4 * i;
                if (f < 74) {
                    const int tg = tbase + 4 * f;
                    f32x4 t;
                    t[0] = ((unsigned)(tg + 0) < (unsigned)T_LEN) ? xrow[tg + 0] : 0.f;
                    t[1] = ((unsigned)(tg + 1) < (unsigned)T_LEN) ? xrow[tg + 1] : 0.f;
                    t[2] = ((unsigned)(tg + 2) < (unsigned)T_LEN) ? xrow[tg + 2] : 0.f;
                    t[3] = ((unsigned)(tg + 3) < (unsigned)T_LEN) ? xrow[tg + 3] : 0.f;
                    v[i] = t;
                }
            }
        }
    };
    // commit: convert + transpose v[] into xs (vmcnt waits happen here, late)
    auto commit = [&]() {
#pragma unroll
        for (int i = 0; i < 19; ++i) {
            const int f = q + 4 * i;
            if (f < 74) {
                const int tt = 4 * f;
                xs[(tt + 0) * PITCH + c] = f2bf(v[i][0]);
                xs[(tt + 1) * PITCH + c] = f2bf(v[i][1]);
                xs[(tt + 2) * PITCH + c] = f2bf(v[i][2]);
                xs[(tt + 3) * PITCH + c] = f2bf(v[i][3]);
            }
        }
    };

    // prologue: stage tile 0
    issue(tg0);
    commit();
    __syncthreads();

    int bbase[4];
#pragma unroll
    for (int nt = 0; nt < 4; ++nt) {
        const int tl = wv * 64 + nt * 16 + l15;
        bbase[nt] = (tl + 3) * PITCH + quad * 8;    // shorts; +3 so roff >= 0
    }
    const short* w2p = W2 + (size_t)lane * 8;
    const size_t outb = ((size_t)(b * 64)) << 16;
    const int dtab[9] = {-17, -16, -15, -1, 0, 1, 15, 16, 17};

    for (int it = 0; it < NTILE; ++it) {
        const int t0 = tg0 + it * NT;
        const bool more = (it + 1 < NTILE);

        // (A) issue next tile's loads -> in flight across the K-loop
        if (more) issue(t0 + NT);

        // (B) K-loop: 18 chunks of 32, 1-chunk software pipeline (R7)
        f32x4 acc[4][4] = {};                       // [mt][nt]
        bf16x8 a_cur[4], b_cur[4], a_nxt[4], b_nxt[4];
        {
            const int roff0 = (dtab[0] + 17) * PITCH + 0;
#pragma unroll
            for (int mt = 0; mt < 4; ++mt)
                a_cur[mt] = *(const bf16x8*)(w2p + (size_t)(0 * 4 + mt) * 512);
#pragma unroll
            for (int nt = 0; nt < 4; ++nt) {
                union { bf16x8 v8; bf16x4 v4[2]; } u;
                u.v4[0] = *(const bf16x4*)(xs + bbase[nt] + roff0);
                u.v4[1] = *(const bf16x4*)(xs + bbase[nt] + roff0 + 4);
                b_cur[nt] = u.v8;
            }
        }
#pragma unroll
        for (int ch = 0; ch < NCHUNK; ++ch) {
            if (ch < NCHUNK - 1) {
                const int chn = ch + 1;
                const int jn = chn >> 1, hn = chn & 1;
                const int roffn = (dtab[jn] + 17) * PITCH + hn * 32;   // compile-time
#pragma unroll
                for (int mt = 0; mt < 4; ++mt)
                    a_nxt[mt] = *(const bf16x8*)(w2p + (size_t)(chn * 4 + mt) * 512);
#pragma unroll
                for (int nt = 0; nt < 4; ++nt) {
                    union { bf16x8 v8; bf16x4 v4[2]; } u;
                    u.v4[0] = *(const bf16x4*)(xs + bbase[nt] + roffn);
                    u.v4[1] = *(const bf16x4*)(xs + bbase[nt] + roffn + 4);
                    b_nxt[nt] = u.v8;
                }
            }
#pragma unroll
            for (int mt = 0; mt < 4; ++mt)
#pragma unroll
                for (int nt = 0; nt < 4; ++nt)
                    acc[mt][nt] = __builtin_amdgcn_mfma_f32_16x16x32_bf16(a_cur[mt], b_cur[nt], acc[mt][nt], 0, 0, 0);
            if (ch < NCHUNK - 1) {
#pragma unroll
                for (int mt = 0; mt < 4; ++mt) { a_cur[mt] = a_nxt[mt]; b_cur[mt] = b_nxt[mt]; }
            }
        }

        // (C..) epilogue via os; commit next tile into xs during p=0 (xs dead here)
        __syncthreads();                            // b1: K-loop xs reads done, os free
#pragma unroll
        for (int p = 0; p < 2; ++p) {
            if (p == 1) __syncthreads();            // b3: p=0 os reads done
#pragma unroll
            for (int mtl = 0; mtl < 2; ++mtl) {
                const int mt = 2 * p + mtl;
#pragma unroll
                for (int r = 0; r < 4; ++r) {
                    const int ol = mtl * 16 + quad * 4 + r;           // 0..31
                    const float bv = bias[mt * 16 + quad * 4 + r];
#pragma unroll
                    for (int nt = 0; nt < 4; ++nt) {
                        const int t = wv * 64 + nt * 16 + l15;
                        os[ol * OPITCH + t] = acc[mt][nt][r] + bv;
                    }
                }
            }
            if (p == 0 && more) commit();           // cvt + ds_write next tile
            __syncthreads();                        // b2/b4: os (and xs) writes visible
#pragma unroll
            for (int i = 0; i < 8; ++i) {
                const int item = tid + 256 * i;     // 0..2047
                const int ol = item >> 6;           // 0..31
                const int f4 = item & 63;           // 0..63
                const f32x4 vv = *(const f32x4*)(os + ol * OPITCH + 4 * f4);
                const int o = p * 32 + ol;
                *(f32x4*)(out + outb + (((size_t)o) << 16) + t0 + 4 * f4) = vv;
            }
        }
    }
}

extern "C" void kernel_launch(void* const* d_in, const int* in_sizes, int n_in,
                              void* d_out, int out_size, void* d_ws, size_t ws_size,
                              hipStream_t stream) {
    const float* x    = (const float*)d_in[0];
    const float* w    = (const float*)d_in[1];
    const float* bias = (const float*)d_in[2];
    float* out = (float*)d_out;
    short* W2  = (short*)d_ws;                      // 4*18*64*8*2 = 73,728 B

    hipLaunchKernelGGL(prep_w_kernel, dim3(18), dim3(256), 0, stream, w, W2);
    hipLaunchKernelGGL(ta_main_kernel, dim3(T_LEN / SPAN, 8), dim3(256), 0, stream,
                       x, W2, bias, out);
}

// Round 5
// 263.679 us; speedup vs baseline: 1.4947x; 1.4947x over previous
//
#include <hip/hip_runtime.h>

// TALayer: deformable 1D conv, fixed integer taps d[j] ∈ {-17,-16,-15,-1,0,1,15,16,17}
// out[b,o,t] = sum_{c,j} W[o,c,j] * x[b,c,t+d[j]] (zero-pad OOB) + bias[o]
// B=8, C=O=64, T=65536. bf16 MFMA GEMM: C[64, B*T] = W[64,576] * Xg[576, B*T].
// R6: plain stores; batched stage loads 215->197us.
// R7: launch_bounds(256,3) + K-loop 1-chunk pipeline + XCD swizzle: 197->133us.
//     WRITE 1.19x, FETCH 82MB. Latency-bound: 23% HBM, MfmaUtil 11%, occ 26% (~2 blk/CU).
// R8 FAILED: 4-tile persistent pipeline -> v[19] live across K-loop spilled
//     (VGPR=128 cap hit, FETCH 400MB/WRITE 297MB = scratch traffic, occ 19%). Reverted.
// R9: TLP play, structure identical to R7. NT 256->128: xs 22.8KB (aliased os
//     16.9KB) -> 7 blk/CU by LDS; acc[4][2]=32 AGPR, peak ~95 regs ->
//     launch_bounds(256,4) comfortable -> 4 blk/CU = 50% occupancy, 4096 blocks.
//     Tripwire: VGPR=128 + FETCH inflation => starved again, retreat to (256,3).

typedef short bf16x8 __attribute__((ext_vector_type(8)));   // 8 bf16 (4 VGPRs)
typedef short bf16x4 __attribute__((ext_vector_type(4)));   // 4 bf16 (8 B, ds_read_b64)
typedef float f32x4  __attribute__((ext_vector_type(4)));   // MFMA accumulator / 16B vec

#define T_LEN   65536
#define NT      128           // t-tile per block
#define ROWS    168           // staged rows: global t in [t0-20, t0+148)
#define PITCH   68            // shorts per LDS row (136 B)
#define LOFF    20            // x[t] -> LDS row (t - t0 + 20)
#define NCHUNK  18            // K = 576 = 18 * 32
#define OPITCH  132           // floats per epilogue LDS row (132 = 4*33, 16B-aligned rows)
#define XS_BYTES (ROWS * PITCH * 2)     // 22,848 B
#define OS_BYTES (32 * OPITCH * 4)      // 16,896 B (aliased into xs region)
#define SMEM_BYTES XS_BYTES             // 22,848 -> 7 blocks/CU by LDS

__device__ __forceinline__ short f2bf(float f) {
    union { float f; unsigned u; } v; v.f = f;
    unsigned u = v.u;
    u += 0x7fffu + ((u >> 16) & 1u);   // round-to-nearest-even
    return (short)(u >> 16);
}

// Weight -> MFMA A-fragment order (bf16), layout [ch][mt][lane][8]:
// W2[((ch*4 + mt)*64 + lane)*8 + i] = bf16(W[o = mt*16 + (lane&15)][kk = ch*32 + (lane>>4)*8 + i])
// kk = j*64 + c -> j = kk>>6, c = kk&63;  W strides [o][c][j] = (576, 9, 1).
__global__ void prep_w_kernel(const float* __restrict__ w, short* __restrict__ W2) {
    int idx = blockIdx.x * 256 + threadIdx.x;       // 0 .. 4607
    if (idx >= 4 * NCHUNK * 64) return;
    int lane = idx & 63;
    int g    = idx >> 6;            // ch*4 + mt
    int ch   = g >> 2;
    int mt   = g & 3;
    int o    = mt * 16 + (lane & 15);
    bf16x8 v;
#pragma unroll
    for (int i = 0; i < 8; ++i) {
        int kk = ch * 32 + (lane >> 4) * 8 + i;
        int j = kk >> 6, c = kk & 63;
        v[i] = f2bf(w[o * 576 + c * 9 + j]);
    }
    *(bf16x8*)(W2 + (size_t)idx * 8) = v;
}

__global__ __launch_bounds__(256, 4)
void ta_main_kernel(const float* __restrict__ x, const short* __restrict__ W2,
                    const float* __restrict__ bias, float* __restrict__ out) {
    __shared__ __align__(16) char smem[SMEM_BYTES];
    short* xs = (short*)smem;                       // staging: [tt][c] bf16, pitch 68
    float* os = (float*)smem;                       // epilogue: [o_local][t] f32, pitch 132

    const int tid  = threadIdx.x;
    const int wv   = tid >> 6;                      // wave -> t-pair (32 t each)
    const int lane = tid & 63;
    const int l15  = lane & 15;
    const int quad = lane >> 4;
    const int b    = blockIdx.y;
    // XCD swizzle: gridDim.x = 512 ≡ 0 mod 8 -> bijective. XCD k owns 64
    // consecutive bx (8192 consecutive t): halo L2 reuse + contiguous writes.
    const int bxd  = blockIdx.x;                    // 0..511
    const int bx   = (bxd & 7) * 64 + (bxd >> 3);
    const int t0   = bx * NT;

    // ---- stage x tile: batched float4 loads, transpose to [tt][c] bf16 in LDS ----
    const int c = tid >> 2;
    const int q = tid & 3;
    const float* xrow = x + (((size_t)(b * 64 + c)) << 16);
    const int tbase = t0 - LOFF;
    const bool interior = (t0 >= LOFF) && (t0 + (ROWS - LOFF) <= T_LEN);

    if (interior) {
        // issue all 11 independent f32x4 loads first, then convert + ds_write
        f32x4 v[11];
#pragma unroll
        for (int i = 0; i < 11; ++i) {
            const int f = q + 4 * i;
            if (f < 42) v[i] = *(const f32x4*)(xrow + tbase + 4 * f);
        }
#pragma unroll
        for (int i = 0; i < 11; ++i) {
            const int f = q + 4 * i;
            if (f < 42) {
                const int tt = 4 * f;
                xs[(tt + 0) * PITCH + c] = f2bf(v[i][0]);
                xs[(tt + 1) * PITCH + c] = f2bf(v[i][1]);
                xs[(tt + 2) * PITCH + c] = f2bf(v[i][2]);
                xs[(tt + 3) * PITCH + c] = f2bf(v[i][3]);
            }
        }
    } else {
        // boundary blocks (2 of 512 along x): scalar clamped path
#pragma unroll
        for (int i = 0; i < 11; ++i) {
            const int f = q + 4 * i;
            if (f < 42) {
                const int tt = 4 * f;
                const int tg = tbase + tt;
                f32x4 v;
                v[0] = ((unsigned)(tg + 0) < (unsigned)T_LEN) ? xrow[tg + 0] : 0.f;
                v[1] = ((unsigned)(tg + 1) < (unsigned)T_LEN) ? xrow[tg + 1] : 0.f;
                v[2] = ((unsigned)(tg + 2) < (unsigned)T_LEN) ? xrow[tg + 2] : 0.f;
                v[3] = ((unsigned)(tg + 3) < (unsigned)T_LEN) ? xrow[tg + 3] : 0.f;
                xs[(tt + 0) * PITCH + c] = f2bf(v[0]);
                xs[(tt + 1) * PITCH + c] = f2bf(v[1]);
                xs[(tt + 2) * PITCH + c] = f2bf(v[2]);
                xs[(tt + 3) * PITCH + c] = f2bf(v[3]);
            }
        }
    }
    __syncthreads();

    // ---- K loop: 18 chunks of 32 (chunk ch: tap j = ch>>1, c-half h = ch&1) ----
    // 1-chunk software pipeline: prefetch (a,b) of chunk ch+1 before MFMAs of ch.
    int bbase[2];
#pragma unroll
    for (int nt = 0; nt < 2; ++nt) {
        const int tl = wv * 32 + nt * 16 + l15;
        bbase[nt] = (tl + 3) * PITCH + quad * 8;    // shorts; +3 so roff >= 0
    }
    const short* w2p = W2 + (size_t)lane * 8;

    f32x4 acc[4][2] = {};                           // [mt][nt]

    const int dtab[9] = {-17, -16, -15, -1, 0, 1, 15, 16, 17};

    bf16x8 a_cur[4], b_cur[2], a_nxt[4], b_nxt[2];

    // prologue: load chunk 0
    {
        const int roff0 = (dtab[0] + 17) * PITCH + 0;
#pragma unroll
        for (int mt = 0; mt < 4; ++mt)
            a_cur[mt] = *(const bf16x8*)(w2p + (size_t)(0 * 4 + mt) * 512);
#pragma unroll
        for (int nt = 0; nt < 2; ++nt) {
            union { bf16x8 v8; bf16x4 v4[2]; } u;
            u.v4[0] = *(const bf16x4*)(xs + bbase[nt] + roff0);
            u.v4[1] = *(const bf16x4*)(xs + bbase[nt] + roff0 + 4);
            b_cur[nt] = u.v8;
        }
    }

#pragma unroll
    for (int ch = 0; ch < NCHUNK; ++ch) {
        if (ch < NCHUNK - 1) {
            const int chn = ch + 1;
            const int jn = chn >> 1, hn = chn & 1;
            const int roffn = (dtab[jn] + 17) * PITCH + hn * 32;   // compile-time
#pragma unroll
            for (int mt = 0; mt < 4; ++mt)
                a_nxt[mt] = *(const bf16x8*)(w2p + (size_t)(chn * 4 + mt) * 512);
#pragma unroll
            for (int nt = 0; nt < 2; ++nt) {
                union { bf16x8 v8; bf16x4 v4[2]; } u;
                u.v4[0] = *(const bf16x4*)(xs + bbase[nt] + roffn);
                u.v4[1] = *(const bf16x4*)(xs + bbase[nt] + roffn + 4);
                b_nxt[nt] = u.v8;
            }
        }
#pragma unroll
        for (int mt = 0; mt < 4; ++mt)
#pragma unroll
            for (int nt = 0; nt < 2; ++nt)
                acc[mt][nt] = __builtin_amdgcn_mfma_f32_16x16x32_bf16(a_cur[mt], b_cur[nt], acc[mt][nt], 0, 0, 0);
        if (ch < NCHUNK - 1) {
#pragma unroll
            for (int mt = 0; mt < 4; ++mt) a_cur[mt] = a_nxt[mt];
#pragma unroll
            for (int nt = 0; nt < 2; ++nt) b_cur[nt] = b_nxt[nt];
        }
    }

    // ---- epilogue: round-trip through LDS so each wave writes contiguous lines ----
    // C/D layout: row(m) = quad*4 + r, col(n) = lane&15
    // Two passes (o in [0,32) then [32,64)), each: acc -> LDS [o_local][t] -> stores.
    const size_t outb = ((size_t)(b * 64)) << 16;
#pragma unroll
    for (int p = 0; p < 2; ++p) {
        __syncthreads();                            // xs reads (p=0) / os reads (p=1) done
#pragma unroll
        for (int mtl = 0; mtl < 2; ++mtl) {
            const int mt = 2 * p + mtl;
#pragma unroll
            for (int r = 0; r < 4; ++r) {
                const int ol = mtl * 16 + quad * 4 + r;           // 0..31
                const float bv = bias[mt * 16 + quad * 4 + r];
#pragma unroll
                for (int nt = 0; nt < 2; ++nt) {
                    const int t = wv * 32 + nt * 16 + l15;
                    os[ol * OPITCH + t] = acc[mt][nt][r] + bv;
                }
            }
        }
        __syncthreads();
        // read back + store: item = [o_local][f4], 32*32 items; 512B contiguous per row
#pragma unroll
        for (int i = 0; i < 4; ++i) {
            const int item = tid + 256 * i;         // 0..1023
            const int ol = item >> 5;               // 0..31
            const int f4 = item & 31;               // 0..31
            const f32x4 v = *(const f32x4*)(os + ol * OPITCH + 4 * f4);
            const int o = p * 32 + ol;
            *(f32x4*)(out + outb + (((size_t)o) << 16) + t0 + 4 * f4) = v;
        }
    }
}

extern "C" void kernel_launch(void* const* d_in, const int* in_sizes, int n_in,
                              void* d_out, int out_size, void* d_ws, size_t ws_size,
                              hipStream_t stream) {
    const float* x    = (const float*)d_in[0];
    const float* w    = (const float*)d_in[1];
    const float* bias = (const float*)d_in[2];
    float* out = (float*)d_out;
    short* W2  = (short*)d_ws;                      // 4*18*64*8*2 = 73,728 B

    hipLaunchKernelGGL(prep_w_kernel, dim3(18), dim3(256), 0, stream, w, W2);
    hipLaunchKernelGGL(ta_main_kernel, dim3(T_LEN / NT, 8), dim3(256), 0, stream,
                       x, W2, bias, out);
}